// Round 11
// baseline (122.205 us; speedup 1.0000x reference)
//
#include <hip/hip_runtime.h>
#include <hip/hip_bf16.h>
#include <math.h>

#define NB 32
#define NS 1024
#define NH 512
#define NE 1024   // 2H
#define NEGV -1e10f

typedef _Float16 f16x8 __attribute__((ext_vector_type(8)));
typedef _Float16 f16x4 __attribute__((ext_vector_type(4)));
typedef float f32x4 __attribute__((ext_vector_type(4)));

__device__ __forceinline__ float fast_tanh(float x) {
  float t = __expf(2.f * x);
  return (t - 1.f) * __builtin_amdgcn_rcpf(t + 1.f);
}

// c[b][h] = b_attn[h] + sum_e hidden[b][e] * W_h[e][h]   (fp32, tiny)
__global__ __launch_bounds__(256) void proj_h_kernel(
    const float* __restrict__ hidden, const float* __restrict__ W_attn,
    const float* __restrict__ b_attn, float* __restrict__ c) {
  int b = blockIdx.x >> 1;
  int h = ((blockIdx.x & 1) << 8) + threadIdx.x;
  __shared__ float hid[NH];
  for (int e = threadIdx.x; e < NH; e += 256) hid[e] = hidden[b * NH + e];
  __syncthreads();
  float acc = b_attn[h];
#pragma unroll 8
  for (int e = 0; e < NH; ++e) acc = fmaf(hid[e], W_attn[(size_t)e * NH + h], acc);
  c[b * NH + h] = acc;
}

// WeT[col][k] = fp16(W_e[k][col]) — transposed so B k-runs are contiguous.
__global__ __launch_bounds__(256) void prep_We_kernel(
    const float* __restrict__ W_attn, _Float16* __restrict__ WeT) {
  int k = blockIdx.x;  // 0..1023
  const float* src = W_attn + (size_t)(NH + k) * NH;
#pragma unroll
  for (int j = 0; j < 2; ++j) {
    int col = threadIdx.x + (j << 8);
    WeT[(size_t)col * NE + k] = (_Float16)src[col];
  }
}

// Fused  tanh(enc@W_e + c) . W_v  partials over a 256-col chunk.
// Tile 128(M)x256(N), BK=64, 512 threads / 8 waves (2M x 4N, wave 64x64).
// SINGLE-buffer LDS (64 KB) + m97 2-barrier loop:
//   STAGE(kt) -> sync (drains) -> COMPUTE(kt) -> sync.
// 2 resident blocks/CU: one block computes while the other drains its stage
// (m97's mechanism — dbuf adds nothing since __syncthreads drains vmcnt(0)).
__global__ __launch_bounds__(512) void score_kernel(
    const float* __restrict__ enc, const _Float16* __restrict__ WeT,
    const float* __restrict__ c, const float* __restrict__ Wv,
    float* __restrict__ spart) {
  __shared__ float Asm[128 * 64];      // fp32, 32 KB, row stride 256 B
  __shared__ _Float16 Bsm[256 * 64];   // fp16, 32 KB, col stride 128 B
  const int tid = threadIdx.x;
  const int lane = tid & 63;
  const int wid = tid >> 6;        // 0..7
  const int wr = wid >> 2;         // wave M-position (0,1)
  const int wc = wid & 3;          // wave N-position (0..3)
  const int r15 = lane & 15;
  const int id = blockIdx.x;                  // 0..511
  const int lb = ((id & 7) << 6) + (id >> 3); // XCD-chunked bijective map
  const int mt = lb >> 1;                     // M-tile of 128 rows
  const int nc = lb & 1;                      // 256-col chunk
  const int b = mt >> 3;
  const int s0 = (mt & 7) << 7;
  const char* Abase = (const char*)(enc + ((size_t)b * NS + s0) * NE);  // 4096 B rows
  const char* Wbase = (const char*)(WeT + ((size_t)(nc << 8)) * NE);    // 2048 B cols

  f32x4 acc[4][4];
#pragma unroll
  for (int i = 0; i < 4; ++i)
#pragma unroll
    for (int j = 0; j < 4; ++j) acc[i][j] = (f32x4)0.f;

  // A LDS: byte d holds linear (row=d>>8, inrow=(d&255)^((row&15)<<4))  [R8/R9: 0 conflicts]
  // B LDS: byte d holds linear (col=d>>7, inrow=(d&127)^((col&7)<<4))   [R8/R9: 0 conflicts]
#define STAGE(KT)                                                                \
  {                                                                              \
    _Pragma("unroll") for (int i = 0; i < 4; ++i) {                              \
      int dbase = (i << 13) + (wid << 10);                                       \
      int d = dbase + (lane << 4);                                               \
      int row = d >> 8;                                                          \
      int sb = (d & 255) ^ ((row & 15) << 4);                                    \
      __builtin_amdgcn_global_load_lds(                                          \
          (const __attribute__((address_space(1))) uint32_t*)(Abase + (size_t)row * 4096 + ((KT) << 8) + sb), \
          (__attribute__((address_space(3))) uint32_t*)((char*)Asm + dbase),     \
          16, 0, 0);                                                             \
    }                                                                            \
    _Pragma("unroll") for (int i = 0; i < 4; ++i) {                              \
      int dbase = (i << 13) + (wid << 10);                                       \
      int d = dbase + (lane << 4);                                               \
      int col = d >> 7;                                                          \
      int sb = (d & 127) ^ ((col & 7) << 4);                                     \
      __builtin_amdgcn_global_load_lds(                                          \
          (const __attribute__((address_space(1))) uint32_t*)(Wbase + (size_t)col * 2048 + ((KT) << 7) + sb), \
          (__attribute__((address_space(3))) uint32_t*)((char*)Bsm + dbase),     \
          16, 0, 0);                                                             \
    }                                                                            \
  }

#define COMPUTE()                                                                \
  _Pragma("unroll") for (int kk = 0; kk < 2; ++kk) {                             \
    f16x8 af[4], bf[4];                                                          \
    _Pragma("unroll") for (int mi = 0; mi < 4; ++mi) {                           \
      int row = (wr << 6) + (mi << 4) + r15;                                     \
      int off1 = (row << 8) + (kk << 7) + ((lane >> 4) << 5);                    \
      int x = (row & 15) << 4;                                                   \
      f32x4 u = *(const f32x4*)((const char*)Asm + (off1 ^ x));                  \
      f32x4 v = *(const f32x4*)((const char*)Asm + ((off1 + 16) ^ x));           \
      f16x8 h;                                                                   \
      h[0] = (_Float16)u[0]; h[1] = (_Float16)u[1];                              \
      h[2] = (_Float16)u[2]; h[3] = (_Float16)u[3];                              \
      h[4] = (_Float16)v[0]; h[5] = (_Float16)v[1];                              \
      h[6] = (_Float16)v[2]; h[7] = (_Float16)v[3];                              \
      af[mi] = h;                                                                \
    }                                                                            \
    _Pragma("unroll") for (int nj = 0; nj < 4; ++nj) {                           \
      int cb = (wc << 6) + (nj << 4) + r15;                                      \
      int off = (cb << 7) + (kk << 6) + ((lane >> 4) << 4);                      \
      off ^= (cb & 7) << 4;                                                      \
      bf[nj] = *(const f16x8*)((const char*)Bsm + off);                          \
    }                                                                            \
    _Pragma("unroll") for (int mi = 0; mi < 4; ++mi)                             \
      _Pragma("unroll") for (int nj = 0; nj < 4; ++nj)                           \
        acc[mi][nj] = __builtin_amdgcn_mfma_f32_16x16x32_f16(af[mi], bf[nj],     \
                                                             acc[mi][nj], 0, 0, 0); \
  }

  for (int kt = 0; kt < 16; ++kt) {
    STAGE(kt);
    __syncthreads();   // drain: all of this step's LDS writes landed
    COMPUTE();
    __syncthreads();   // all reads done before next step's STAGE overwrites
  }
#undef STAGE
#undef COMPUTE

  // ---- epilogue: fast-tanh + W_v dot over this wave's 64 cols ----
  float sr[4][4];
#pragma unroll
  for (int i = 0; i < 4; ++i)
#pragma unroll
    for (int r = 0; r < 4; ++r) sr[i][r] = 0.f;
#pragma unroll
  for (int nj = 0; nj < 4; ++nj) {
    int hcol = (nc << 8) + (wc << 6) + (nj << 4) + r15;
    float wvj = Wv[hcol];
    float cvj = c[b * NH + hcol];
#pragma unroll
    for (int mi = 0; mi < 4; ++mi)
#pragma unroll
      for (int r = 0; r < 4; ++r)
        sr[mi][r] += wvj * fast_tanh(acc[mi][nj][r] + cvj);
  }
  // reduce across the 16 col-lanes (fixed order -> deterministic)
#pragma unroll
  for (int off = 1; off < 16; off <<= 1)
#pragma unroll
    for (int mi = 0; mi < 4; ++mi)
#pragma unroll
      for (int r = 0; r < 4; ++r) sr[mi][r] += __shfl_xor(sr[mi][r], off, 64);
  if (r15 == 0) {
    float* dst = spart + (size_t)((nc << 2) + wc) * NB * NS + b * NS + s0 + (wr << 6);
#pragma unroll
    for (int mi = 0; mi < 4; ++mi)
#pragma unroll
      for (int r = 0; r < 4; ++r)
        dst[(mi << 4) + ((lane >> 4) << 2) + r] = sr[mi][r];
  }
}

// masked softmax over S per batch row; sums the 8 score partials first
__global__ __launch_bounds__(256) void softmax_kernel(
    const float* __restrict__ spart, const int* __restrict__ mask,
    float* __restrict__ attn) {
  int b = blockIdx.x, tid = threadIdx.x;
  __shared__ float red[8];
  float v[4];
  float mx = -INFINITY;
#pragma unroll
  for (int j = 0; j < 4; ++j) {
    int s = tid + (j << 8);
    float x = 0.f;
#pragma unroll
    for (int p = 0; p < 8; ++p) x += spart[(size_t)p * NB * NS + b * NS + s];
    v[j] = (mask[b * NS + s] == 0) ? NEGV : x;
    mx = fmaxf(mx, v[j]);
  }
#pragma unroll
  for (int off = 32; off >= 1; off >>= 1) mx = fmaxf(mx, __shfl_xor(mx, off, 64));
  if ((tid & 63) == 0) red[tid >> 6] = mx;
  __syncthreads();
  mx = fmaxf(fmaxf(red[0], red[1]), fmaxf(red[2], red[3]));
  float sum = 0.f;
#pragma unroll
  for (int j = 0; j < 4; ++j) {
    v[j] = __expf(v[j] - mx);
    sum += v[j];
  }
#pragma unroll
  for (int off = 32; off >= 1; off >>= 1) sum += __shfl_xor(sum, off, 64);
  __syncthreads();
  if ((tid & 63) == 0) red[4 + (tid >> 6)] = sum;
  __syncthreads();
  float inv = 1.f / (red[4] + red[5] + red[6] + red[7]);
#pragma unroll
  for (int j = 0; j < 4; ++j) attn[b * NS + tid + (j << 8)] = v[j] * inv;
}

// partial context over a 64-row S chunk (fp32 enc)
__global__ __launch_bounds__(256) void ctx_partial_kernel(
    const float* __restrict__ enc, const float* __restrict__ attn,
    float* __restrict__ partial) {
  int ch = blockIdx.x;  // 0..15
  int b = blockIdx.y;
  int tid = threadIdx.x;
  __shared__ float w[64];
  if (tid < 64) w[tid] = attn[b * NS + (ch << 6) + tid];
  __syncthreads();
  const float* encb = enc + ((size_t)b * NS + (ch << 6)) * NE;
  float4 acc = make_float4(0.f, 0.f, 0.f, 0.f);
  int e = tid << 2;
  for (int s = 0; s < 64; ++s) {
    float4 x = *(const float4*)(encb + (size_t)s * NE + e);
    float ws_ = w[s];
    acc.x = fmaf(ws_, x.x, acc.x);
    acc.y = fmaf(ws_, x.y, acc.y);
    acc.z = fmaf(ws_, x.z, acc.z);
    acc.w = fmaf(ws_, x.w, acc.w);
  }
  *(float4*)(partial + ((size_t)(b * 16 + ch)) * NE + e) = acc;
}

__global__ __launch_bounds__(256) void ctx_reduce_kernel(
    const float* __restrict__ partial, float* __restrict__ ctx) {
  int b = blockIdx.x;
  int e = threadIdx.x << 2;
  float4 acc = make_float4(0.f, 0.f, 0.f, 0.f);
  for (int ch = 0; ch < 16; ++ch) {
    float4 x = *(const float4*)(partial + ((size_t)(b * 16 + ch)) * NE + e);
    acc.x += x.x;
    acc.y += x.y;
    acc.z += x.z;
    acc.w += x.w;
  }
  *(float4*)(ctx + (size_t)b * NE + e) = acc;
}

extern "C" void kernel_launch(void* const* d_in, const int* in_sizes, int n_in,
                              void* d_out, int out_size, void* d_ws, size_t ws_size,
                              hipStream_t stream) {
  const float* hidden = (const float*)d_in[0];
  const float* enc = (const float*)d_in[1];
  const int* mask = (const int*)d_in[2];
  const float* W_attn = (const float*)d_in[3];
  const float* b_attn = (const float*)d_in[4];
  const float* W_v = (const float*)d_in[5];

  float* ctx = (float*)d_out;   // context: 32*1024
  float* attn = ctx + NB * NS;  // attn_w: 32*1024

  char* ws = (char*)d_ws;
  float* c = (float*)ws;                             // 64 KB
  float* spart = (float*)(ws + 65536);               // 8*32*1024 f32 = 1 MB
  float* partial = (float*)(ws + 65536 + 1048576);   // 32*16*1024 f32 = 2 MB
  _Float16* WeT = (_Float16*)(ws + 65536 + 1048576 + 2097152);  // 1 MB

  proj_h_kernel<<<64, 256, 0, stream>>>(hidden, W_attn, b_attn, c);
  prep_We_kernel<<<NE, 256, 0, stream>>>(W_attn, WeT);
  score_kernel<<<512, 512, 0, stream>>>(enc, WeT, c, W_v, spart);
  softmax_kernel<<<NB, 256, 0, stream>>>(spart, mask, attn);
  ctx_partial_kernel<<<dim3(16, NB), 256, 0, stream>>>(enc, attn, partial);
  ctx_reduce_kernel<<<NB, 256, 0, stream>>>(partial, ctx);
}